// Round 1
// baseline (75.172 us; speedup 1.0000x reference)
//
#include <hip/hip_runtime.h>
#include <stdint.h>

#define HW 65536
#define WIMG 256
#define TOPK 100
#define CAP 4096

// Monotone float->uint key (handles negatives for safety; data is [0,1)).
__device__ __forceinline__ uint32_t fkey(float v) {
    uint32_t b = __float_as_uint(v);
    return b ^ ((b & 0x80000000u) ? 0xFFFFFFFFu : 0x80000000u);
}

// ws layout (floats):
// [0      , 6400 ) xs of hm_p topk   (b*100 + j)
// [6400   , 12800) xs of hm_t topk
// [12800  , 19200) ys of hm_p topk
// [19200  , 25600) ys of hm_t topk
// [25600  , 25728) per-batch partials: (loss_sum, mask_sum) * 64

__global__ __launch_bounds__(256) void topk_kernel(
    const float* __restrict__ hm_p, const float* __restrict__ hm_t,
    float* __restrict__ ws)
{
    __shared__ unsigned long long cand[CAP];
    __shared__ uint32_t s_cnt;
    __shared__ uint32_t s_kthr, s_klo, s_khi;

    const int tid = threadIdx.x;
    const int bi  = blockIdx.x;
    const int which = bi & 1;           // 0 = hm_p, 1 = hm_t
    const int b     = bi >> 1;
    const float* src = (which ? hm_t : hm_p) + (size_t)b * HW;
    const float4* src4 = (const float4*)src;

    if (tid == 0) {
        s_kthr = fkey(0.99f);           // good first guess for uniform [0,1)
        s_klo  = 0u;                    // count(key>klo) = N  (too many)
        s_khi  = 0xFFFFFFFFu;           // count(key>khi) = 0  (too few)
    }
    __syncthreads();

    // Threshold-collect with bisection fallback: need 100 <= cnt <= CAP.
    for (int it = 0; it < 48; ++it) {
        if (tid == 0) s_cnt = 0;
        __syncthreads();
        const uint32_t kthr = s_kthr;
        for (int t = 0; t < HW / 4 / 256; ++t) {
            float4 v = src4[tid + t * 256];
            const int base = (tid + t * 256) * 4;
            float f[4] = {v.x, v.y, v.z, v.w};
            #pragma unroll
            for (int e = 0; e < 4; ++e) {
                uint32_t uk = fkey(f[e]);
                if (uk > kthr) {
                    uint32_t pos = atomicAdd(&s_cnt, 1u);
                    if (pos < CAP)
                        cand[pos] = ((unsigned long long)uk << 16) |
                                    (unsigned long long)(65535 - (base + e));
                }
            }
        }
        __syncthreads();
        const uint32_t cnt = s_cnt;                 // uniform across block
        if (cnt >= TOPK && cnt <= CAP) break;
        if (tid == 0) {
            if (cnt < TOPK) { s_khi = s_kthr; s_kthr = s_klo + ((s_kthr - s_klo) >> 1); }
            else            { s_klo = s_kthr; s_kthr = s_kthr + ((s_khi - s_kthr) >> 1); }
        }
        __syncthreads();
    }

    const int cnt = (int)min(s_cnt, (uint32_t)CAP);
    int M = 1024;
    while (M < cnt) M <<= 1;                        // M in {1024,2048,4096}
    for (int i = tid; i < M; i += 256) if (i >= cnt) cand[i] = 0ull;
    __syncthreads();

    // Bitonic sort, descending by composite key (value desc, index asc).
    for (int len = 2; len <= M; len <<= 1) {
        for (int inc = len >> 1; inc > 0; inc >>= 1) {
            for (int i = tid; i < M; i += 256) {
                int j = i ^ inc;
                if (j > i) {
                    bool desc = ((i & len) == 0);
                    unsigned long long a = cand[i], c = cand[j];
                    if ((a < c) == desc) { cand[i] = c; cand[j] = a; }
                }
            }
            __syncthreads();
        }
    }

    const int obase = which * 6400 + b * TOPK;
    for (int j = tid; j < TOPK; j += 256) {
        unsigned long long key = cand[j];
        uint32_t idx = 65535u - (uint32_t)(key & 0xFFFFull);
        ws[obase + j]         = (float)(idx & (WIMG - 1));  // x = idx % W
        ws[12800 + obase + j] = (float)(idx >> 8);          // y = idx / W
    }
}

__device__ __forceinline__ float gwd(float px, float py, float pw, float ph, float pr,
                                     float tx, float ty, float tw, float th, float trg)
{
    pw = fminf(fmaxf(pw, 1e-7f), 1e7f);  ph = fminf(fmaxf(ph, 1e-7f), 1e7f);
    tw = fminf(fmaxf(tw, 1e-7f), 1e7f);  th = fminf(fmaxf(th, 1e-7f), 1e7f);
    const float d2r = 0.017453292519943295f;
    float rp = pr * d2r, rt = trg * d2r;
    float cp = cosf(rp), sp = sinf(rp);
    float ct = cosf(rt), st = sinf(rt);
    float ap = 0.5f * pw, bp = 0.5f * ph;
    float at = 0.5f * tw, bt = 0.5f * th;
    float ap2 = ap * ap, bp2 = bp * bp, at2 = at * at, bt2 = bt * bt;
    float p00 = ap2 * cp * cp + bp2 * sp * sp;
    float p11 = ap2 * sp * sp + bp2 * cp * cp;
    float p01 = (ap2 - bp2) * cp * sp;
    float t00 = at2 * ct * ct + bt2 * st * st;
    float t11 = at2 * st * st + bt2 * ct * ct;
    float t01 = (at2 - bt2) * ct * st;
    float dx = px - tx, dy = py - ty;
    float xyd = dx * dx + dy * dy;
    float whr = ap2 + bp2 + at2 + bt2;
    float trc = p00 * t00 + 2.f * p01 * t01 + p11 * t11;
    float dets = (ap * bp) * (at * bt);
    whr -= 2.f * sqrtf(fmaxf(trc + 2.f * dets, 0.f));
    float dist = fmaxf(xyd + whr, 0.f);
    float d = log1pf(dist);
    return 1.f - 1.f / (1.f + d);
}

__global__ __launch_bounds__(128) void loss_kernel(
    const float* __restrict__ ab_p,  const float* __restrict__ ang_p,
    const float* __restrict__ ab_t,  const float* __restrict__ ang_t,
    const int*   __restrict__ ind,   const int*   __restrict__ reg_mask,
    const float* __restrict__ ws,    float* __restrict__ partials)
{
    const int b = blockIdx.x;
    const int j = threadIdx.x;
    float loss = 0.f, msum = 0.f;
    if (j < TOPK) {
        float m = (float)reg_mask[b * TOPK + j];
        msum = m;
        int id = ind[b * TOPK + j];
        float xp = ws[b * TOPK + j];
        float xt = ws[6400 + b * TOPK + j];
        float yp = ws[12800 + b * TOPK + j];
        float yt = ws[19200 + b * TOPK + j];
        float ab0 = ab_p[(size_t)(b * 2 + 0) * HW + id];
        float ab1 = ab_p[(size_t)(b * 2 + 1) * HW + id];
        float ang = ang_p[(size_t)b * HW + id];
        float px = xp * m, py = yp * m;
        float pw = 2.f * ab0 * m, ph = 2.f * ab1 * m;
        float pr = (ang - 90.f) * m;
        float tx = xt * m, ty = yt * m;
        float tw = 2.f * ab_t[b * 200 + j * 2 + 0] * m;
        float th = 2.f * ab_t[b * 200 + j * 2 + 1] * m;
        float trg = (ang_t[b * TOPK + j] - 90.f) * m;
        loss = gwd(px, py, pw, ph, pr, tx, ty, tw, th, trg);
    }
    // reduce 128 threads = 2 waves
    #pragma unroll
    for (int off = 32; off > 0; off >>= 1) {
        loss += __shfl_down(loss, off);
        msum += __shfl_down(msum, off);
    }
    __shared__ float sl[2], sm[2];
    if ((threadIdx.x & 63) == 0) { sl[threadIdx.x >> 6] = loss; sm[threadIdx.x >> 6] = msum; }
    __syncthreads();
    if (threadIdx.x == 0) {
        partials[b * 2]     = sl[0] + sl[1];
        partials[b * 2 + 1] = sm[0] + sm[1];
    }
}

__global__ void finalize_kernel(const float* __restrict__ partials, float* __restrict__ out)
{
    float L = 0.f, M = 0.f;
    for (int i = 0; i < 64; ++i) { L += partials[2 * i]; M += partials[2 * i + 1]; }
    out[0] = L / (M + 1e-8f);
}

extern "C" void kernel_launch(void* const* d_in, const int* in_sizes, int n_in,
                              void* d_out, int out_size, void* d_ws, size_t ws_size,
                              hipStream_t stream)
{
    const float* hm_p  = (const float*)d_in[0];
    const float* ab_p  = (const float*)d_in[1];
    const float* ang_p = (const float*)d_in[2];
    const float* hm_t  = (const float*)d_in[3];
    const float* ab_t  = (const float*)d_in[4];
    const float* ang_t = (const float*)d_in[5];
    const int*   ind      = (const int*)d_in[6];
    const int*   reg_mask = (const int*)d_in[7];
    float* ws  = (float*)d_ws;
    float* out = (float*)d_out;

    topk_kernel<<<128, 256, 0, stream>>>(hm_p, hm_t, ws);
    loss_kernel<<<64, 128, 0, stream>>>(ab_p, ang_p, ab_t, ang_t, ind, reg_mask,
                                        ws, ws + 25600);
    finalize_kernel<<<1, 1, 0, stream>>>(ws + 25600, out);
}